// Round 7
// baseline (159.590 us; speedup 1.0000x reference)
//
#include <hip/hip_runtime.h>

#define Bb 2
#define Ll 1024
#define Dd 256
#define Ee 64
#define Tt 8

typedef float f4 __attribute__((ext_vector_type(4)));

// K1: fold output projection into per-type transforms, stored TRANSPOSED:
// M1t[t][d][e] = sum_m W[e][m]     * LT[t][m][d]
// M2t[t][d][e] = sum_m W[e][256+m] * RT[t][m][d]
// grid = Tt*32 = 256 blocks (t, pair of e), 128 threads: ec=tid>>6, d4=tid&63.
__global__ __launch_bounds__(128) void combine_kernel(const float* __restrict__ LT,
                                                      const float* __restrict__ RT,
                                                      const float* __restrict__ W,
                                                      float* __restrict__ M1t,
                                                      float* __restrict__ M2t) {
    int t  = blockIdx.x >> 5;
    int e0 = (blockIdx.x & 31) * 2;
    int tid = threadIdx.x;
    int ec = tid >> 6;
    int d4 = tid & 63;

    __shared__ float s_w1[2][Dd];
    __shared__ float s_w2[2][Dd];
    {   // stage 2 rows of W (each 512 floats = 128 f4) with f4 loads
        const f4* w4 = (const f4*)(W + e0 * 2 * Dd);   // 256 f4 total
        #pragma unroll
        for (int k = 0; k < 2; ++k) {
            int idx = tid + k * 128;
            f4 v = w4[idx];
            int row = idx >> 7;
            int c   = idx & 127;
            if (c < 64) *((f4*)&s_w1[row][0] + c)        = v;
            else        *((f4*)&s_w2[row][0] + (c - 64)) = v;
        }
    }
    __syncthreads();

    const f4* lt4 = (const f4*)(LT + t * Dd * Dd) + d4;  // row stride = 64 f4
    const f4* rt4 = (const f4*)(RT + t * Dd * Dd) + d4;
    f4 a1 = {0.f, 0.f, 0.f, 0.f}, a2 = {0.f, 0.f, 0.f, 0.f};
    #pragma unroll 8
    for (int m = 0; m < Dd; ++m) {
        f4 lv = lt4[m * 64];          // 1 KB/wave coalesced
        f4 rv = rt4[m * 64];
        a1 += s_w1[ec][m] * lv;
        a2 += s_w2[ec][m] * rv;
    }
    int e = e0 + ec;
    // transposed scatter store: 2 MB total into L2-resident ws — cheap
    #pragma unroll
    for (int j = 0; j < 4; ++j) {
        M1t[(t * Dd + d4 * 4 + j) * Ee + e] = a1[j];
        M2t[(t * Dd + d4 * 4 + j) * Ee + e] = a2[j];
    }
}

// K2: lp[b][l][e] = sum_d M1t[t][d][e]*emb[b][l][d], rp likewise. t = types[b][l].
// Lanes = consecutive e -> every M-load is 256B coalesced.
__global__ __launch_bounds__(256) void proj_kernel(const float* __restrict__ emb,
                                                   const int* __restrict__ types,
                                                   const float* __restrict__ M1t,
                                                   const float* __restrict__ M2t,
                                                   float* __restrict__ lp,
                                                   float* __restrict__ rp) {
    int bl = blockIdx.x;       // grid = B*L
    int tid = threadIdx.x;     // e = tid&63, chunk = tid>>6 (quarter of d)
    __shared__ float s_e[Dd];
    s_e[tid] = emb[bl * Dd + tid];
    __syncthreads();
    int t = types[bl];
    int e = tid & 63;
    int chunk = tid >> 6;
    const float* m1 = M1t + (size_t)t * Dd * Ee + e;
    const float* m2 = M2t + (size_t)t * Dd * Ee + e;
    float a1 = 0.f, a2 = 0.f;
    #pragma unroll 8
    for (int dd = 0; dd < 64; ++dd) {
        int d = chunk * 64 + dd;
        float s = s_e[d];               // wave-uniform -> LDS broadcast
        a1 = fmaf(m1[d * Ee], s, a1);   // 256B coalesced across lanes
        a2 = fmaf(m2[d * Ee], s, a2);
    }
    __shared__ float r1[256], r2[256];
    r1[tid] = a1;
    r2[tid] = a2;
    __syncthreads();
    if (tid < 64) {
        lp[bl * Ee + tid] = r1[tid] + r1[tid + 64] + r1[tid + 128] + r1[tid + 192];
        rp[bl * Ee + tid] = r2[tid] + r2[tid + 64] + r2[tid + 128] + r2[tid + 192];
    }
}

// K3 (the bulk): out[b][l][m][e] = lp[b][l][e] + rp[b][m][e] + bias[e]
// grid = 1024 blocks = b(2) x mchunk(16, 64 m each) x lrange(32, 32 l each).
// Per thread: 4 rp f4 (+bias) in registers for the whole block, then a
// near-pure store stream. A/B vs round 6: PLAIN stores (the fill kernel
// proves plain streaming stores hit 6.6 TB/s through L2 write-combining;
// nontemporal bypasses L2 and may lose burst-combining).
__global__ __launch_bounds__(256) void bcast_kernel(const float* __restrict__ lp,
                                                    const float* __restrict__ rp,
                                                    const float* __restrict__ bias,
                                                    f4* __restrict__ out) {
    int blk = blockIdx.x;
    int lr = blk & 31;             // l-range (32 l values)
    int mc = (blk >> 5) & 15;      // m-chunk (64 m values)
    int b  = blk >> 9;
    int tid = threadIdx.x;
    int e4 = tid & 15;             // f4 within e-dim
    int ml = tid >> 4;             // m slot within 16

    const f4* rp4 = (const f4*)rp;
    const f4* lp4 = (const f4*)lp;
    f4 bb = ((const f4*)bias)[e4];

    f4 rv[4];
    #pragma unroll
    for (int k = 0; k < 4; ++k) {  // rp chunk + bias -> 16 VGPRs, kept all kernel
        int m = mc * 64 + k * 16 + ml;
        rv[k] = rp4[((size_t)b * Ll + m) * 16 + e4] + bb;
    }

    int l0 = lr * 32;
    #pragma unroll 4
    for (int li = 0; li < 32; ++li) {
        int l = l0 + li;
        f4 lv = lp4[((size_t)b * Ll + l) * 16 + e4];   // one 256B line/wave
        f4* o = out + (((size_t)b * Ll + l) * Ll + mc * 64) * 16;
        #pragma unroll
        for (int k = 0; k < 4; ++k) {
            int moff = k * 16 + ml;
            o[moff * 16 + e4] = lv + rv[k];            // plain store (A/B vs nt)
        }
    }
}

extern "C" void kernel_launch(void* const* d_in, const int* in_sizes, int n_in,
                              void* d_out, int out_size, void* d_ws, size_t ws_size,
                              hipStream_t stream) {
    const float* emb   = (const float*)d_in[0];  // (B,L,D)
    const int*   types = (const int*)d_in[1];    // (B,L)
    const float* LT    = (const float*)d_in[2];  // (T,D,D)
    const float* RT    = (const float*)d_in[3];  // (T,D,D)
    const float* W     = (const float*)d_in[4];  // (E,2D)
    const float* bias  = (const float*)d_in[5];  // (E,)

    float* ws = (float*)d_ws;
    float* M1t = ws;                      // T*D*E = 131072 floats
    float* M2t = M1t + Tt * Dd * Ee;      // 131072
    float* lp  = M2t + Tt * Dd * Ee;      // B*L*E = 131072
    float* rp  = lp + Bb * Ll * Ee;       // 131072   (total 2 MiB)

    combine_kernel<<<Tt * 32, 128, 0, stream>>>(LT, RT, W, M1t, M2t);
    proj_kernel<<<Bb * Ll, 256, 0, stream>>>(emb, types, M1t, M2t, lp, rp);
    bcast_kernel<<<Bb * 16 * 32, 256, 0, stream>>>(lp, rp, bias, (f4*)d_out);
}